// Round 17
// baseline (990.935 us; speedup 1.0000x reference)
//
#include <hip/hip_runtime.h>

// Problem constants
#define BS   1024        // B*S rows
#define DD   1024        // D (= K)
#define VV   32000       // V
#define TOPK 50
#define TOPPF 0.95f
#define NVTOT 32768000ull   // BS*VV

typedef __attribute__((ext_vector_type(8)))  short bf16x8;
typedef __attribute__((ext_vector_type(16))) float f32x16;
typedef __attribute__((ext_vector_type(4)))  int   i32x4;

#define MFMA32(A,B,C) __builtin_amdgcn_mfma_f32_32x32x16_bf16(A, B, C, 0, 0, 0)

// ---------------------------------------------------------------- utilities
__device__ __forceinline__ unsigned fkey(float f) {
  unsigned u = __float_as_uint(f);
  return (u & 0x80000000u) ? ~u : (u | 0x80000000u);
}
__device__ __forceinline__ unsigned rotl32(unsigned x, int r) {
  return (x << r) | (x >> (32 - r));
}
__device__ __forceinline__ ushort f2bf(float f) {   // fp32 -> bf16 RNE
  unsigned u = __float_as_uint(f);
  unsigned r = ((u >> 16) & 1u) + 0x7FFFu;
  return (ushort)((u + r) >> 16);
}
__device__ __forceinline__ float bf2f(ushort h) {
  return __uint_as_float(((unsigned)h) << 16);
}
__device__ __forceinline__ bf16x8 negbf(bf16x8 a) {  // flip sign of 8 bf16
  i32x4 t = __builtin_bit_cast(i32x4, a);
  t = t ^ 0x80008000;
  return __builtin_bit_cast(bf16x8, t);
}

// JAX threefry2x32-20, key=(0,42), partitionable: counter (0, i), bits = w0^w1.
__device__ float gumbel_at(unsigned i) {
  unsigned x0 = 0u, x1 = i;
  const unsigned ks0 = 0u, ks1 = 42u, ks2 = 0x1BD11BDAu ^ 0u ^ 42u;
  x0 += ks0; x1 += ks1;
  const int rotA[4] = {13, 15, 26, 6};
  const int rotB[4] = {17, 29, 16, 24};
#define TF_R4(R) { x0 += x1; x1 = rotl32(x1, R[0]); x1 ^= x0; \
                   x0 += x1; x1 = rotl32(x1, R[1]); x1 ^= x0; \
                   x0 += x1; x1 = rotl32(x1, R[2]); x1 ^= x0; \
                   x0 += x1; x1 = rotl32(x1, R[3]); x1 ^= x0; }
  TF_R4(rotA); x0 += ks1; x1 += ks2 + 1u;
  TF_R4(rotB); x0 += ks2; x1 += ks0 + 2u;
  TF_R4(rotA); x0 += ks0; x1 += ks1 + 3u;
  TF_R4(rotB); x0 += ks1; x1 += ks2 + 4u;
  TF_R4(rotA); x0 += ks2; x1 += ks0 + 5u;
#undef TF_R4
  unsigned bits = x0 ^ x1;
  float f = __uint_as_float(0x3F800000u | (bits >> 9)) - 1.0f;
  float u = fmaxf(f, 1.17549435e-38f);
  return -logf(-logf(u));
}

// ------------------------------------------------- split fp32 -> bf16 hi/lo
__global__ __launch_bounds__(256) void pack_split(
    const float* __restrict__ xr, const float* __restrict__ xi,
    ushort* __restrict__ ohr, ushort* __restrict__ olr,
    ushort* __restrict__ ohi, ushort* __restrict__ oli,
    float si, int n4) {
  int g = blockIdx.x * 256 + threadIdx.x;
  if (g >= n4) return;
  int i = g * 4;
  float4 a = *(const float4*)(xr + i);
  float4 b = *(const float4*)(xi + i);
  float av[4] = {a.x, a.y, a.z, a.w};
  float bv[4] = {b.x * si, b.y * si, b.z * si, b.w * si};
  unsigned hr[4], lr[4], hi_[4], li[4];
#pragma unroll
  for (int j = 0; j < 4; ++j) {
    ushort h = f2bf(av[j]);          hr[j] = h;
    lr[j] = f2bf(av[j] - bf2f(h));
    ushort h2 = f2bf(bv[j]);         hi_[j] = h2;
    li[j] = f2bf(bv[j] - bf2f(h2));
  }
  uint2 w;
  w.x = hr[0] | (hr[1] << 16); w.y = hr[2] | (hr[3] << 16);
  *(uint2*)(ohr + i) = w;
  w.x = lr[0] | (lr[1] << 16); w.y = lr[2] | (lr[3] << 16);
  *(uint2*)(olr + i) = w;
  w.x = hi_[0] | (hi_[1] << 16); w.y = hi_[2] | (hi_[3] << 16);
  *(uint2*)(ohi + i) = w;
  w.x = li[0] | (li[1] << 16); w.y = li[2] | (li[3] << 16);
  *(uint2*)(oli + i) = w;
}

// ---------------------------------------------------------------- MFMA GEMM
// R8 frame (block 128x128, 8 waves 2Mx4N, wave tile 64x32, BK=32, dbuf LDS,
// 2-barrier loop, XCD remap) with 32x32x16 MFMA instead of 16x16x32:
// same 24 ds_read_b128/wave/step, 17% fewer MFMA cycles (48 MFMA32 @8.07cy
// vs 96 MFMA16 @4.85cy). A/B layout row=lane&31, k=(lane>>5)*8+j; C/D map
// col=lane&31, row=(reg&3)+8*(reg>>2)+4*(lane>>5) (validated R12).
__global__ __launch_bounds__(512) void gemm_mfma(
    const ushort* __restrict__ APk,                      // [4][1024][1024]
    const ushort* __restrict__ Wrh, const ushort* __restrict__ Wrl,
    const ushort* __restrict__ Wih, const ushort* __restrict__ Wil,
    float* __restrict__ amp) {
  __shared__ ushort lds[2][8][4096];   // 2 bufs x 8 tiles x (128r x 32k) = 128KB
  const int tid = threadIdx.x;
  const int lane = tid & 63, wid = tid >> 6;
  const int d = blockIdx.x;
  const int x = d & 7, s = d >> 3;
  const int bm = ((x >> 1) << 1) | (s & 1);       // bm-pair per XCD
  const int bn = (x & 1) * 125 + (s >> 1);        // bn-half per XCD
  const int row0 = bm << 7, col0 = bn << 7;
  const int wm = wid >> 2, wn = wid & 3;          // wave grid 2(M) x 4(N)

  const ushort* tp[8] = {APk, APk + (1 << 20), APk + (2 << 20), APk + (3 << 20),
                         Wrh, Wrl, Wih, Wil};

  // staging addressing (per thread, step-invariant part) -- identical to R8
  const int rrow = tid >> 2;                     // tile row 0..127
  const int ss = (tid & 3) ^ (rrow & 3) ^ ((rrow >> 2) & 3);  // src slot
  const size_t offA = (size_t)(row0 + rrow) * DD + (ss << 3);
  const size_t offB = (size_t)(col0 + rrow) * DD + (ss << 3);

  f32x16 accr[2] = {}, acci[2] = {};

  // read-side LDS byte offsets: [m][kh] for A, [kh] for B.
  // logical 16B slot = kh*2 + (lane>>5); physical = logical ^ (r&3) ^ ((r>>2)&3)
  int aoff[2][2], boff[2];
#pragma unroll
  for (int m = 0; m < 2; ++m) {
    const int ar = (wm << 6) + (m << 5) + (lane & 31);
#pragma unroll
    for (int h = 0; h < 2; ++h)
      aoff[m][h] = (ar << 6) +
          ((((h << 1) + (lane >> 5)) ^ (ar & 3) ^ ((ar >> 2) & 3)) << 4);
  }
  {
    const int br = (wn << 5) + (lane & 31);
#pragma unroll
    for (int h = 0; h < 2; ++h)
      boff[h] = (br << 6) +
          ((((h << 1) + (lane >> 5)) ^ (br & 3) ^ ((br >> 2) & 3)) << 4);
  }

#define STAGE(buf, step) {                                                   \
    const int k0 = (step) << 5;                                              \
    _Pragma("unroll")                                                        \
    for (int t = 0; t < 8; ++t) {                                            \
      const ushort* src = tp[t] + ((t < 4) ? offA : offB) + k0;              \
      __builtin_amdgcn_global_load_lds(                                      \
          (const __attribute__((address_space(1))) unsigned int*)src,        \
          (__attribute__((address_space(3))) unsigned int*)&lds[buf][t][wid << 9], \
          16, 0, 0);                                                         \
    }                                                                        \
  }

  STAGE(0, 0);
  __syncthreads();
  int cur = 0;
  for (int step = 0; step < 32; ++step) {
    if (step + 1 < 32) STAGE(cur ^ 1, step + 1);
    const char* L0 = (const char*)&lds[cur][0][0];
    const char* L1 = (const char*)&lds[cur][1][0];
    const char* L2 = (const char*)&lds[cur][2][0];
    const char* L3 = (const char*)&lds[cur][3][0];
    const char* L4 = (const char*)&lds[cur][4][0];
    const char* L5 = (const char*)&lds[cur][5][0];
    const char* L6 = (const char*)&lds[cur][6][0];
    const char* L7 = (const char*)&lds[cur][7][0];
#pragma unroll
    for (int h = 0; h < 2; ++h) {      // two k16 units per BK=32 step
      bf16x8 bRh = *(const bf16x8*)(L4 + boff[h]);
      bf16x8 bRl = *(const bf16x8*)(L5 + boff[h]);
      bf16x8 bIh = *(const bf16x8*)(L6 + boff[h]);
      bf16x8 bIl = *(const bf16x8*)(L7 + boff[h]);
#pragma unroll
      for (int m = 0; m < 2; ++m) {
        bf16x8 aPrh = *(const bf16x8*)(L0 + aoff[m][h]);
        bf16x8 aPrl = *(const bf16x8*)(L1 + aoff[m][h]);
        bf16x8 aNih = *(const bf16x8*)(L2 + aoff[m][h]);
        bf16x8 aNil = *(const bf16x8*)(L3 + aoff[m][h]);
        bf16x8 aPih = negbf(aNih);
        bf16x8 aPil = negbf(aNil);
        f32x16 r = accr[m], q = acci[m];
        r = MFMA32(aPrh, bRh, r); r = MFMA32(aPrh, bRl, r); r = MFMA32(aPrl, bRh, r);
        r = MFMA32(aNih, bIh, r); r = MFMA32(aNih, bIl, r); r = MFMA32(aNil, bIh, r);
        q = MFMA32(aPih, bRh, q); q = MFMA32(aPih, bRl, q); q = MFMA32(aPil, bRh, q);
        q = MFMA32(aPrh, bIh, q); q = MFMA32(aPrh, bIl, q); q = MFMA32(aPrl, bIh, q);
        accr[m] = r; acci[m] = q;
      }
    }
    __syncthreads();   // drains vmcnt(0): next buffer staged; all reads done
    cur ^= 1;
  }
#undef STAGE
  // epilogue: 32x32 C/D map: col = lane&31, row = (reg&3)+8*(reg>>2)+4*(lane>>5)
#pragma unroll
  for (int m = 0; m < 2; ++m) {
    f32x16 r = accr[m], q = acci[m];
    const int colg = col0 + (wn << 5) + (lane & 31);
    const int rowb = row0 + (wm << 6) + (m << 5) + ((lane >> 5) << 2);
#pragma unroll
    for (int reg = 0; reg < 16; ++reg) {
      const int row = rowb + (reg & 3) + ((reg >> 2) << 3);
      float vr = r[reg], vi = q[reg];
      amp[(size_t)row * VV + colg] = vr * vr + vi * vi;
    }
  }
}

// ---------------------------------------------------------- fused row post
// 1024 threads; shfl-based reductions (scratch overlaid on hist); logprobs
// pass merged into the probs/gumbel pass.
__global__ __launch_bounds__(1024) void post_row(
    const float* __restrict__ amp, const float* __restrict__ bias,
    float* __restrict__ logits, float* __restrict__ logprobs,
    float* __restrict__ probs, float* __restrict__ tokens) {
  __shared__ __align__(16) float lg[VV];      // 128000 B
  __shared__ int hist[4096];                  // 16384 B (also reduce scratch)
  __shared__ int iscan[512];                  // 2048 B
  __shared__ float sval[768]; __shared__ int sidx[768];
  __shared__ float ssv[768];  __shared__ int ssi[768];
  __shared__ int scnt;
  __shared__ float sh_f[4];   // 0:red-out 1:mx2 2:dk 3:vb
  __shared__ int   sh_i[4];   // 0:chunk 1:bin 2:ib

  const int row = blockIdx.x, tid = threadIdx.x;
  const int lane = tid & 63, wv = tid >> 6;   // 16 waves
  const float* A = amp + (size_t)row * VV;
  float* Lg = logits + (size_t)row * VV;
  float* Lp = logprobs + (size_t)row * VV;
  float* P  = probs + (size_t)row * VV;
  float* redf = (float*)hist;                 // 16 wave partials

  // pass 1: load amp -> LDS, row sum (wave shfl + serial-16 tail)
  float s = 0.f;
  for (int i = tid; i < VV / 4; i += 1024) {
    float4 a = ((const float4*)A)[i];
    ((float4*)lg)[i] = a;
    s += a.x + a.y + a.z + a.w;
  }
#pragma unroll
  for (int o = 32; o > 0; o >>= 1) s += __shfl_down(s, o, 64);
  if (lane == 0) redf[wv] = s;
  __syncthreads();
  if (tid == 0) {
    float t = 0.f;
    for (int j = 0; j < 16; ++j) t += redf[j];
    sh_f[0] = t * (1.0f / (float)VV) * 1e-6f + 1e-30f;
  }
  __syncthreads();
  const float floorv = sh_f[0];
  __syncthreads();

  // pass 2: logits = log(amp+floor)+bias; store LDS + global; track max
  float mx = -INFINITY;
  for (int i = tid; i < VV / 4; i += 1024) {
    float4 a = ((float4*)lg)[i];
    float4 b = ((const float4*)bias)[i];
    float4 l;
    l.x = logf(a.x + floorv) + b.x;
    l.y = logf(a.y + floorv) + b.y;
    l.z = logf(a.z + floorv) + b.z;
    l.w = logf(a.w + floorv) + b.w;
    ((float4*)lg)[i] = l;
    ((float4*)Lg)[i] = l;
    mx = fmaxf(mx, fmaxf(fmaxf(l.x, l.y), fmaxf(l.z, l.w)));
  }
#pragma unroll
  for (int o = 32; o > 0; o >>= 1) mx = fmaxf(mx, __shfl_down(mx, o, 64));
  if (lane == 0) redf[wv] = mx;
  __syncthreads();
  if (tid == 0) {
    float t = -INFINITY;
    for (int j = 0; j < 16; ++j) t = fmaxf(t, redf[j]);
    sh_f[0] = t;
  }
  __syncthreads();
  mx = sh_f[0];
  __syncthreads();

  // pass 3: sumexp
  float se = 0.f;
  for (int i = tid; i < VV / 4; i += 1024) {
    float4 l = ((float4*)lg)[i];
    se += expf(l.x - mx) + expf(l.y - mx) + expf(l.z - mx) + expf(l.w - mx);
  }
#pragma unroll
  for (int o = 32; o > 0; o >>= 1) se += __shfl_down(se, o, 64);
  if (lane == 0) redf[wv] = se;
  __syncthreads();
  if (tid == 0) {
    float t = 0.f;
    for (int j = 0; j < 16; ++j) t += redf[j];
    sh_f[0] = mx + logf(t);
  }
  __syncthreads();
  const float lse = sh_f[0];
  __syncthreads();   // redf (hist) free after this point

  // pass 4: 12-bit histogram of fkey(logits)
  for (int i = tid; i < 4096; i += 1024) hist[i] = 0;
  if (tid == 0) scnt = 0;
  __syncthreads();
  for (int v = tid; v < VV; v += 1024)
    atomicAdd(&hist[fkey(lg[v]) >> 20], 1);
  __syncthreads();
  // descending chunks of 8 bins; inclusive scan over 512 chunks (tid<512)
  {
    if (tid < 512) {
      const int hi = 4095 - 8 * tid;
      int part = 0;
#pragma unroll
      for (int j = 0; j < 8; ++j) part += hist[hi - j];
      iscan[tid] = part;
    }
    __syncthreads();
    for (int off = 1; off < 512; off <<= 1) {
      int add = (tid < 512 && tid >= off) ? iscan[tid - off] : 0;
      __syncthreads();
      if (tid < 512) iscan[tid] += add;
      __syncthreads();
    }
    if (tid < 512) {
      int cum = iscan[tid], prev = tid ? iscan[tid - 1] : 0;
      if (cum >= TOPK && prev < TOPK) sh_i[0] = tid;
    }
    __syncthreads();
    if (tid == 0) {
      int tc = sh_i[0];
      int c = tc ? iscan[tc - 1] : 0;
      int b = 4095 - 8 * tc;
      for (int j = 0; j < 8; ++j) {
        int h = hist[4095 - 8 * tc - j];
        if (c + h >= TOPK) { b = 4095 - 8 * tc - j; break; }
        c += h;
      }
      sh_i[1] = b;
    }
    __syncthreads();
  }
  const unsigned binb = (unsigned)sh_i[1];

  // gather survivors (all elems in bins >= binb; superset of top-k)
  for (int v = tid; v < VV; v += 1024) {
    if ((fkey(lg[v]) >> 20) >= binb) {
      int p = atomicAdd(&scnt, 1);
      if (p < 768) { sval[p] = lg[v]; sidx[p] = v; }
    }
  }
  __syncthreads();
  const int n = min(scnt, 768);
  // rank sort: value desc, index asc (stable argsort(-filt) order)
  for (int i = tid; i < n; i += 1024) {
    float vi = sval[i]; int ii = sidx[i]; int r = 0;
    for (int j = 0; j < n; ++j) {
      float vj = sval[j]; int ij = sidx[j];
      r += (vj > vi) || (vj == vi && ij < ii);
    }
    ssv[r] = vi; ssi[r] = ii;
  }
  __syncthreads();
  if (tid == 0) {
    const float kthv = ssv[TOPK - 1];
    int np = TOPK;
    while (np < n && ssv[np] >= kthv) ++np;
    const float mx2 = ssv[0];
    float denom = 0.f;
    for (int j = 0; j < np; ++j) denom += expf(ssv[j] - mx2);
    float cum = 0.f; int m = np;
    for (int j = 0; j < np; ++j) {
      float sp = expf(ssv[j] - mx2) / denom;
      cum += sp;
      if (cum - sp >= TOPPF) { m = j; break; }
    }
    float dk = 0.f;
    for (int j = 0; j < m; ++j) dk += expf(ssv[j] - mx2);
    sh_f[1] = mx2; sh_f[2] = dk; sh_f[3] = ssv[m - 1];
    sh_i[2] = ssi[m - 1];
  }
  __syncthreads();
  const float mx2 = sh_f[1], dk = sh_f[2], vb = sh_f[3];
  const int ib = sh_i[2];

  // pass 5: logprobs + probs + gumbel argmax (merged single sweep)
  float best = -INFINITY; int bidx = 0x7FFFFFFF;
  for (int i = tid; i < VV / 4; i += 1024) {
    float4 l4 = ((float4*)lg)[i];
    float lv[4] = {l4.x, l4.y, l4.z, l4.w};
    float4 o4 = {l4.x - lse, l4.y - lse, l4.z - lse, l4.w - lse};
    ((float4*)Lp)[i] = o4;
    float pv[4] = {0.f, 0.f, 0.f, 0.f};
#pragma unroll
    for (int j = 0; j < 4; ++j) {
      const int v = i * 4 + j;
      float l = lv[j];
      bool kept = (l > vb) || (l == vb && v <= ib);
      if (kept) {
        pv[j] = expf(l - mx2) / dk;
        float g = gumbel_at((unsigned)(row * VV + v));
        float sc = l + g;
        if (sc > best || (sc == best && v < bidx)) { best = sc; bidx = v; }
      }
    }
    float4 p4 = {pv[0], pv[1], pv[2], pv[3]};
    ((float4*)P)[i] = p4;
  }
  // argmax reduce: wave shfl, then serial-16 (scratch = hist space)
#pragma unroll
  for (int o = 32; o > 0; o >>= 1) {
    float ov = __shfl_down(best, o, 64);
    int   oi = __shfl_down(bidx, o, 64);
    if (ov > best || (ov == best && oi < bidx)) { best = ov; bidx = oi; }
  }
  {
    float* wv_v = (float*)hist;          // 16 floats
    int*   wv_i = hist + 16;             // 16 ints
    if (lane == 0) { wv_v[wv] = best; wv_i[wv] = bidx; }
    __syncthreads();
    if (tid == 0) {
      float bv = -INFINITY; int bi = 0x7FFFFFFF;
      for (int j = 0; j < 16; ++j) {
        if (wv_v[j] > bv || (wv_v[j] == bv && wv_i[j] < bi)) { bv = wv_v[j]; bi = wv_i[j]; }
      }
      tokens[row] = (float)bi;
    }
  }
}

// ---------------------------------------------------------------- launcher
extern "C" void kernel_launch(void* const* d_in, const int* in_sizes, int n_in,
                              void* d_out, int out_size, void* d_ws, size_t ws_size,
                              hipStream_t stream) {
  const float* pr   = (const float*)d_in[0];
  const float* pi   = (const float*)d_in[1];
  const float* wr   = (const float*)d_in[2];
  const float* wi   = (const float*)d_in[3];
  const float* bias = (const float*)d_in[4];

  float* out      = (float*)d_out;
  float* logits   = out;                       // [1024, 32000]
  float* logprobs = out + NVTOT;               // [1024, 32000]
  float* ampsq    = out + 2 * NVTOT;           // [1024, 32000]
  float* tokens   = out + 3 * NVTOT;           // [1024]
  float* probs    = out + 3 * NVTOT + 1024;    // [1024, 32000]

  // scratch-in-output: W bf16 packs live in logits+logprobs (overwritten by
  // post_row AFTER the GEMM); psi packs live in probs (overwritten last).
  ushort* Wrh = (ushort*)logits;               // [32000][1024] each
  ushort* Wrl = Wrh + 32768000;
  ushort* Wih = (ushort*)logprobs;
  ushort* Wil = Wih + 32768000;
  ushort* APk = (ushort*)probs;                // [4][1024][1024]

  // pack psi (negated imag) and W into bf16 hi/lo
  pack_split<<<1024, 256, 0, stream>>>(pr, pi,
      APk, APk + (1 << 20), APk + (2 << 20), APk + (3 << 20), -1.0f, 262144);
  pack_split<<<32000, 256, 0, stream>>>(wr, wi,
      Wrh, Wrl, Wih, Wil, 1.0f, 8192000);

  gemm_mfma<<<2000, 512, 0, stream>>>(APk, Wrh, Wrl, Wih, Wil, ampsq);

  post_row<<<BS, 1024, 0, stream>>>(ampsq, bias, logits, logprobs, probs, tokens);
}

// Round 19
// 919.480 us; speedup vs baseline: 1.0777x; 1.0777x over previous
//
#include <hip/hip_runtime.h>

// Problem constants
#define BS   1024        // B*S rows
#define DD   1024        // D (= K)
#define VV   32000       // V
#define TOPK 50
#define TOPPF 0.95f
#define NVTOT 32768000ull   // BS*VV

typedef __attribute__((ext_vector_type(8))) short bf16x8;
typedef __attribute__((ext_vector_type(4))) float f32x4;
typedef __attribute__((ext_vector_type(4))) int   i32x4;

#define MFMA(A,B,C) __builtin_amdgcn_mfma_f32_16x16x32_bf16(A, B, C, 0, 0, 0)

// ---------------------------------------------------------------- utilities
__device__ __forceinline__ unsigned fkey(float f) {
  unsigned u = __float_as_uint(f);
  return (u & 0x80000000u) ? ~u : (u | 0x80000000u);
}
__device__ __forceinline__ unsigned rotl32(unsigned x, int r) {
  return (x << r) | (x >> (32 - r));
}
__device__ __forceinline__ ushort f2bf(float f) {   // fp32 -> bf16 RNE
  unsigned u = __float_as_uint(f);
  unsigned r = ((u >> 16) & 1u) + 0x7FFFu;
  return (ushort)((u + r) >> 16);
}
__device__ __forceinline__ float bf2f(ushort h) {
  return __uint_as_float(((unsigned)h) << 16);
}
__device__ __forceinline__ bf16x8 negbf(bf16x8 a) {  // flip sign of 8 bf16
  i32x4 t = __builtin_bit_cast(i32x4, a);
  t = t ^ 0x80008000;
  return __builtin_bit_cast(bf16x8, t);
}

// JAX threefry2x32-20, key=(0,42), partitionable: counter (0, i), bits = w0^w1.
__device__ float gumbel_at(unsigned i) {
  unsigned x0 = 0u, x1 = i;
  const unsigned ks0 = 0u, ks1 = 42u, ks2 = 0x1BD11BDAu ^ 0u ^ 42u;
  x0 += ks0; x1 += ks1;
  const int rotA[4] = {13, 15, 26, 6};
  const int rotB[4] = {17, 29, 16, 24};
#define TF_R4(R) { x0 += x1; x1 = rotl32(x1, R[0]); x1 ^= x0; \
                   x0 += x1; x1 = rotl32(x1, R[1]); x1 ^= x0; \
                   x0 += x1; x1 = rotl32(x1, R[2]); x1 ^= x0; \
                   x0 += x1; x1 = rotl32(x1, R[3]); x1 ^= x0; }
  TF_R4(rotA); x0 += ks1; x1 += ks2 + 1u;
  TF_R4(rotB); x0 += ks2; x1 += ks0 + 2u;
  TF_R4(rotA); x0 += ks0; x1 += ks1 + 3u;
  TF_R4(rotB); x0 += ks1; x1 += ks2 + 4u;
  TF_R4(rotA); x0 += ks2; x1 += ks0 + 5u;
#undef TF_R4
  unsigned bits = x0 ^ x1;
  float f = __uint_as_float(0x3F800000u | (bits >> 9)) - 1.0f;
  float u = fmaxf(f, 1.17549435e-38f);
  return -logf(-logf(u));
}

// ------------------------------------------------- split fp32 -> bf16 hi/lo
__device__ __forceinline__ void pack4(
    const float* __restrict__ xr, const float* __restrict__ xi,
    ushort* __restrict__ ohr, ushort* __restrict__ olr,
    ushort* __restrict__ ohi, ushort* __restrict__ oli,
    float si, int i) {
  float4 a = *(const float4*)(xr + i);
  float4 b = *(const float4*)(xi + i);
  float av[4] = {a.x, a.y, a.z, a.w};
  float bv[4] = {b.x * si, b.y * si, b.z * si, b.w * si};
  unsigned hr[4], lr[4], hi_[4], li[4];
#pragma unroll
  for (int j = 0; j < 4; ++j) {
    ushort h = f2bf(av[j]);          hr[j] = h;
    lr[j] = f2bf(av[j] - bf2f(h));
    ushort h2 = f2bf(bv[j]);         hi_[j] = h2;
    li[j] = f2bf(bv[j] - bf2f(h2));
  }
  uint2 w;
  w.x = hr[0] | (hr[1] << 16); w.y = hr[2] | (hr[3] << 16);
  *(uint2*)(ohr + i) = w;
  w.x = lr[0] | (lr[1] << 16); w.y = lr[2] | (lr[3] << 16);
  *(uint2*)(olr + i) = w;
  w.x = hi_[0] | (hi_[1] << 16); w.y = hi_[2] | (hi_[3] << 16);
  *(uint2*)(ohi + i) = w;
  w.x = li[0] | (li[1] << 16); w.y = li[2] | (li[3] << 16);
  *(uint2*)(oli + i) = w;
}

// single launch: blocks [0,1024) pack psi (imag negated); rest pack W.
__global__ __launch_bounds__(256) void pack_all(
    const float* __restrict__ pr, const float* __restrict__ pi,
    ushort* __restrict__ APk,
    const float* __restrict__ wr, const float* __restrict__ wi,
    ushort* __restrict__ Wrh, ushort* __restrict__ Wrl,
    ushort* __restrict__ Wih, ushort* __restrict__ Wil) {
  const int b = blockIdx.x;
  if (b < 1024) {
    int g = b * 256 + threadIdx.x;                 // n4 = 262144
    pack4(pr, pi, APk, APk + (1 << 20), APk + (2 << 20), APk + (3 << 20),
          -1.0f, g * 4);
  } else {
    int g = (b - 1024) * 256 + threadIdx.x;        // n4 = 8192000
    pack4(wr, wi, Wrh, Wrl, Wih, Wil, 1.0f, g * 4);
  }
}

// ---------------------------------------------------------------- MFMA GEMM
// R16 configuration verbatim (best measured: 645us, MfmaUtil 60%).
// amp_sq = |(Pr + iPi) . (Wr + iWi)|^2, split-bf16 (3-term), 12 MFMA/frag-pair.
// Block 128x128, 8 waves (2x4), wave tile 64x32, BK=32, double-buffered LDS,
// 2-barrier loop, XCD-partition remap.
__global__ __launch_bounds__(512) void gemm_mfma(
    const ushort* __restrict__ APk,                      // [4][1024][1024]
    const ushort* __restrict__ Wrh, const ushort* __restrict__ Wrl,
    const ushort* __restrict__ Wih, const ushort* __restrict__ Wil,
    float* __restrict__ amp) {
  __shared__ ushort lds[2][8][4096];   // 2 bufs x 8 tiles x (128r x 32k) = 128KB
  const int tid = threadIdx.x;
  const int lane = tid & 63, wid = tid >> 6;
  const int d = blockIdx.x;
  const int x = d & 7, s = d >> 3;
  const int bm = ((x >> 1) << 1) | (s & 1);       // bm-pair per XCD
  const int bn = (x & 1) * 125 + (s >> 1);        // bn-half per XCD
  const int row0 = bm << 7, col0 = bn << 7;
  const int wm = wid >> 2, wn = wid & 3;          // wave grid 2(M) x 4(N)

  const ushort* tp[8] = {APk, APk + (1 << 20), APk + (2 << 20), APk + (3 << 20),
                         Wrh, Wrl, Wih, Wil};

  // staging addressing (per thread, step-invariant part)
  const int rrow = tid >> 2;                     // tile row 0..127
  const int ss = (tid & 3) ^ (rrow & 3) ^ ((rrow >> 2) & 3);  // src slot
  const size_t offA = (size_t)(row0 + rrow) * DD + (ss << 3);
  const size_t offB = (size_t)(col0 + rrow) * DD + (ss << 3);

  f32x4 accr[4][2] = {}, acci[4][2] = {};

  // compute-side LDS byte offsets (step-invariant)
  int aoff[4], boff[2];
#pragma unroll
  for (int m = 0; m < 4; ++m) {
    const int ar = (wm << 6) + (m << 4) + (lane & 15);
    aoff[m] = (ar << 6) + ((((lane >> 4)) ^ (ar & 3) ^ ((ar >> 2) & 3)) << 4);
  }
#pragma unroll
  for (int n = 0; n < 2; ++n) {
    const int br = (wn << 5) + (n << 4) + (lane & 15);
    boff[n] = (br << 6) + ((((lane >> 4)) ^ (br & 3) ^ ((br >> 2) & 3)) << 4);
  }

#define STAGE(buf, step) {                                                   \
    const int k0 = (step) << 5;                                              \
    _Pragma("unroll")                                                        \
    for (int t = 0; t < 8; ++t) {                                            \
      const ushort* src = tp[t] + ((t < 4) ? offA : offB) + k0;              \
      __builtin_amdgcn_global_load_lds(                                      \
          (const __attribute__((address_space(1))) unsigned int*)src,        \
          (__attribute__((address_space(3))) unsigned int*)&lds[buf][t][wid << 9], \
          16, 0, 0);                                                         \
    }                                                                        \
  }

  STAGE(0, 0);
  __syncthreads();
  int cur = 0;
  for (int step = 0; step < 32; ++step) {
    if (step + 1 < 32) STAGE(cur ^ 1, step + 1);
    const char* L0 = (const char*)&lds[cur][0][0];
    const char* L1 = (const char*)&lds[cur][1][0];
    const char* L2 = (const char*)&lds[cur][2][0];
    const char* L3 = (const char*)&lds[cur][3][0];
    const char* L4 = (const char*)&lds[cur][4][0];
    const char* L5 = (const char*)&lds[cur][5][0];
    const char* L6 = (const char*)&lds[cur][6][0];
    const char* L7 = (const char*)&lds[cur][7][0];
    bf16x8 aPrh[4], aPrl[4], aNih[4], aNil[4], aPih[4], aPil[4];
#pragma unroll
    for (int m = 0; m < 4; ++m) {
      aPrh[m] = *(const bf16x8*)(L0 + aoff[m]);
      aPrl[m] = *(const bf16x8*)(L1 + aoff[m]);
      aNih[m] = *(const bf16x8*)(L2 + aoff[m]);
      aNil[m] = *(const bf16x8*)(L3 + aoff[m]);
      aPih[m] = negbf(aNih[m]);
      aPil[m] = negbf(aNil[m]);
    }
#pragma unroll
    for (int n = 0; n < 2; ++n) {
      bf16x8 bRh = *(const bf16x8*)(L4 + boff[n]);
      bf16x8 bRl = *(const bf16x8*)(L5 + boff[n]);
      bf16x8 bIh = *(const bf16x8*)(L6 + boff[n]);
      bf16x8 bIl = *(const bf16x8*)(L7 + boff[n]);
#pragma unroll
      for (int m = 0; m < 4; ++m) {
        f32x4 r = accr[m][n], q = acci[m][n];
        r = MFMA(aPrh[m], bRh, r); r = MFMA(aPrh[m], bRl, r); r = MFMA(aPrl[m], bRh, r);
        r = MFMA(aNih[m], bIh, r); r = MFMA(aNih[m], bIl, r); r = MFMA(aNil[m], bIh, r);
        q = MFMA(aPih[m], bRh, q); q = MFMA(aPih[m], bRl, q); q = MFMA(aPil[m], bRh, q);
        q = MFMA(aPrh[m], bIh, q); q = MFMA(aPrh[m], bIl, q); q = MFMA(aPrl[m], bIh, q);
        accr[m][n] = r; acci[m][n] = q;
      }
    }
    __syncthreads();   // drains vmcnt(0): next buffer staged; all reads done
    cur ^= 1;
  }
#undef STAGE
  // epilogue: C/D mapping col=lane&15, row=(lane>>4)*4+reg
#pragma unroll
  for (int m = 0; m < 4; ++m)
#pragma unroll
    for (int n = 0; n < 2; ++n)
#pragma unroll
      for (int qi = 0; qi < 4; ++qi) {
        const int row = row0 + (wm << 6) + (m << 4) + ((lane >> 4) << 2) + qi;
        const int col = col0 + (wn << 5) + (n << 4) + (lane & 15);
        float vr = accr[m][n][qi], vi = acci[m][n][qi];
        amp[(size_t)row * VV + col] = vr * vr + vi * vi;
      }
}

// ---------------------------------------------------------- fused row post
// 1024 threads; shfl-based reductions (scratch overlaid on hist); logprobs
// merged into the probs/gumbel pass; streaming outputs via nontemporal stores
// (through clang ext_vector f32x4 -- HIP float4 is rejected by the builtin).
__global__ __launch_bounds__(1024) void post_row(
    const float* __restrict__ amp, const float* __restrict__ bias,
    float* __restrict__ logits, float* __restrict__ logprobs,
    float* __restrict__ probs, float* __restrict__ tokens) {
  __shared__ __align__(16) float lg[VV];      // 128000 B
  __shared__ int hist[4096];                  // 16384 B (also reduce scratch)
  __shared__ int iscan[512];                  // 2048 B
  __shared__ float sval[768]; __shared__ int sidx[768];
  __shared__ float ssv[768];  __shared__ int ssi[768];
  __shared__ int scnt;
  __shared__ float sh_f[4];   // 0:red-out 1:mx2 2:dk 3:vb
  __shared__ int   sh_i[4];   // 0:chunk 1:bin 2:ib

  const int row = blockIdx.x, tid = threadIdx.x;
  const int lane = tid & 63, wv = tid >> 6;   // 16 waves
  const float* A = amp + (size_t)row * VV;
  float* Lg = logits + (size_t)row * VV;
  float* Lp = logprobs + (size_t)row * VV;
  float* P  = probs + (size_t)row * VV;
  float* redf = (float*)hist;                 // 16 wave partials

  // pass 1: load amp -> LDS, row sum (wave shfl + serial-16 tail)
  float s = 0.f;
  for (int i = tid; i < VV / 4; i += 1024) {
    float4 a = ((const float4*)A)[i];
    ((float4*)lg)[i] = a;
    s += a.x + a.y + a.z + a.w;
  }
#pragma unroll
  for (int o = 32; o > 0; o >>= 1) s += __shfl_down(s, o, 64);
  if (lane == 0) redf[wv] = s;
  __syncthreads();
  if (tid == 0) {
    float t = 0.f;
    for (int j = 0; j < 16; ++j) t += redf[j];
    sh_f[0] = t * (1.0f / (float)VV) * 1e-6f + 1e-30f;
  }
  __syncthreads();
  const float floorv = sh_f[0];
  __syncthreads();

  // pass 2: logits = log(amp+floor)+bias; store LDS + global (NT); track max
  float mx = -INFINITY;
  for (int i = tid; i < VV / 4; i += 1024) {
    float4 a = ((float4*)lg)[i];
    float4 b = ((const float4*)bias)[i];
    f32x4 l;
    l.x = logf(a.x + floorv) + b.x;
    l.y = logf(a.y + floorv) + b.y;
    l.z = logf(a.z + floorv) + b.z;
    l.w = logf(a.w + floorv) + b.w;
    ((f32x4*)lg)[i] = l;
    __builtin_nontemporal_store(l, (f32x4*)Lg + i);
    mx = fmaxf(mx, fmaxf(fmaxf(l.x, l.y), fmaxf(l.z, l.w)));
  }
#pragma unroll
  for (int o = 32; o > 0; o >>= 1) mx = fmaxf(mx, __shfl_down(mx, o, 64));
  if (lane == 0) redf[wv] = mx;
  __syncthreads();
  if (tid == 0) {
    float t = -INFINITY;
    for (int j = 0; j < 16; ++j) t = fmaxf(t, redf[j]);
    sh_f[0] = t;
  }
  __syncthreads();
  mx = sh_f[0];
  __syncthreads();

  // pass 3: sumexp
  float se = 0.f;
  for (int i = tid; i < VV / 4; i += 1024) {
    float4 l = ((float4*)lg)[i];
    se += expf(l.x - mx) + expf(l.y - mx) + expf(l.z - mx) + expf(l.w - mx);
  }
#pragma unroll
  for (int o = 32; o > 0; o >>= 1) se += __shfl_down(se, o, 64);
  if (lane == 0) redf[wv] = se;
  __syncthreads();
  if (tid == 0) {
    float t = 0.f;
    for (int j = 0; j < 16; ++j) t += redf[j];
    sh_f[0] = mx + logf(t);
  }
  __syncthreads();
  const float lse = sh_f[0];
  __syncthreads();   // redf (hist) free after this point

  // pass 4: 12-bit histogram of fkey(logits)
  for (int i = tid; i < 4096; i += 1024) hist[i] = 0;
  if (tid == 0) scnt = 0;
  __syncthreads();
  for (int v = tid; v < VV; v += 1024)
    atomicAdd(&hist[fkey(lg[v]) >> 20], 1);
  __syncthreads();
  // descending chunks of 8 bins; inclusive scan over 512 chunks (tid<512)
  {
    if (tid < 512) {
      const int hi = 4095 - 8 * tid;
      int part = 0;
#pragma unroll
      for (int j = 0; j < 8; ++j) part += hist[hi - j];
      iscan[tid] = part;
    }
    __syncthreads();
    for (int off = 1; off < 512; off <<= 1) {
      int add = (tid < 512 && tid >= off) ? iscan[tid - off] : 0;
      __syncthreads();
      if (tid < 512) iscan[tid] += add;
      __syncthreads();
    }
    if (tid < 512) {
      int cum = iscan[tid], prev = tid ? iscan[tid - 1] : 0;
      if (cum >= TOPK && prev < TOPK) sh_i[0] = tid;
    }
    __syncthreads();
    if (tid == 0) {
      int tc = sh_i[0];
      int c = tc ? iscan[tc - 1] : 0;
      int b = 4095 - 8 * tc;
      for (int j = 0; j < 8; ++j) {
        int h = hist[4095 - 8 * tc - j];
        if (c + h >= TOPK) { b = 4095 - 8 * tc - j; break; }
        c += h;
      }
      sh_i[1] = b;
    }
    __syncthreads();
  }
  const unsigned binb = (unsigned)sh_i[1];

  // gather survivors (all elems in bins >= binb; superset of top-k)
  for (int v = tid; v < VV; v += 1024) {
    if ((fkey(lg[v]) >> 20) >= binb) {
      int p = atomicAdd(&scnt, 1);
      if (p < 768) { sval[p] = lg[v]; sidx[p] = v; }
    }
  }
  __syncthreads();
  const int n = min(scnt, 768);
  // rank sort: value desc, index asc (stable argsort(-filt) order)
  for (int i = tid; i < n; i += 1024) {
    float vi = sval[i]; int ii = sidx[i]; int r = 0;
    for (int j = 0; j < n; ++j) {
      float vj = sval[j]; int ij = sidx[j];
      r += (vj > vi) || (vj == vi && ij < ii);
    }
    ssv[r] = vi; ssi[r] = ii;
  }
  __syncthreads();
  if (tid == 0) {
    const float kthv = ssv[TOPK - 1];
    int np = TOPK;
    while (np < n && ssv[np] >= kthv) ++np;
    const float mx2 = ssv[0];
    float denom = 0.f;
    for (int j = 0; j < np; ++j) denom += expf(ssv[j] - mx2);
    float cum = 0.f; int m = np;
    for (int j = 0; j < np; ++j) {
      float sp = expf(ssv[j] - mx2) / denom;
      cum += sp;
      if (cum - sp >= TOPPF) { m = j; break; }
    }
    float dk = 0.f;
    for (int j = 0; j < m; ++j) dk += expf(ssv[j] - mx2);
    sh_f[1] = mx2; sh_f[2] = dk; sh_f[3] = ssv[m - 1];
    sh_i[2] = ssi[m - 1];
  }
  __syncthreads();
  const float mx2 = sh_f[1], dk = sh_f[2], vb = sh_f[3];
  const int ib = sh_i[2];

  // pass 5: logprobs + probs + gumbel argmax (merged single sweep, NT stores)
  float best = -INFINITY; int bidx = 0x7FFFFFFF;
  for (int i = tid; i < VV / 4; i += 1024) {
    float4 l4 = ((float4*)lg)[i];
    float lv[4] = {l4.x, l4.y, l4.z, l4.w};
    f32x4 o4 = {l4.x - lse, l4.y - lse, l4.z - lse, l4.w - lse};
    __builtin_nontemporal_store(o4, (f32x4*)Lp + i);
    float pv[4] = {0.f, 0.f, 0.f, 0.f};
#pragma unroll
    for (int j = 0; j < 4; ++j) {
      const int v = i * 4 + j;
      float l = lv[j];
      bool kept = (l > vb) || (l == vb && v <= ib);
      if (kept) {
        pv[j] = expf(l - mx2) / dk;
        float g = gumbel_at((unsigned)(row * VV + v));
        float sc = l + g;
        if (sc > best || (sc == best && v < bidx)) { best = sc; bidx = v; }
      }
    }
    f32x4 p4 = {pv[0], pv[1], pv[2], pv[3]};
    __builtin_nontemporal_store(p4, (f32x4*)P + i);
  }
  // argmax reduce: wave shfl, then serial-16 (scratch = hist space)
#pragma unroll
  for (int o = 32; o > 0; o >>= 1) {
    float ov = __shfl_down(best, o, 64);
    int   oi = __shfl_down(bidx, o, 64);
    if (ov > best || (ov == best && oi < bidx)) { best = ov; bidx = oi; }
  }
  {
    float* wv_v = (float*)hist;          // 16 floats
    int*   wv_i = hist + 16;             // 16 ints
    if (lane == 0) { wv_v[wv] = best; wv_i[wv] = bidx; }
    __syncthreads();
    if (tid == 0) {
      float bv = -INFINITY; int bi = 0x7FFFFFFF;
      for (int j = 0; j < 16; ++j) {
        if (wv_v[j] > bv || (wv_v[j] == bv && wv_i[j] < bi)) { bv = wv_v[j]; bi = wv_i[j]; }
      }
      tokens[row] = (float)bi;
    }
  }
}

// ---------------------------------------------------------------- launcher
extern "C" void kernel_launch(void* const* d_in, const int* in_sizes, int n_in,
                              void* d_out, int out_size, void* d_ws, size_t ws_size,
                              hipStream_t stream) {
  const float* pr   = (const float*)d_in[0];
  const float* pi   = (const float*)d_in[1];
  const float* wr   = (const float*)d_in[2];
  const float* wi   = (const float*)d_in[3];
  const float* bias = (const float*)d_in[4];

  float* out      = (float*)d_out;
  float* logits   = out;                       // [1024, 32000]
  float* logprobs = out + NVTOT;               // [1024, 32000]
  float* ampsq    = out + 2 * NVTOT;           // [1024, 32000]
  float* tokens   = out + 3 * NVTOT;           // [1024]
  float* probs    = out + 3 * NVTOT + 1024;    // [1024, 32000]

  // scratch-in-output: W bf16 packs live in logits+logprobs (overwritten by
  // post_row AFTER the GEMM); psi packs live in probs (overwritten last).
  ushort* Wrh = (ushort*)logits;               // [32000][1024] each
  ushort* Wrl = Wrh + 32768000;
  ushort* Wih = (ushort*)logprobs;
  ushort* Wil = Wih + 32768000;
  ushort* APk = (ushort*)probs;                // [4][1024][1024]

  // pack psi (negated imag) and W into bf16 hi/lo -- single launch
  pack_all<<<33024, 256, 0, stream>>>(pr, pi, APk, wr, wi, Wrh, Wrl, Wih, Wil);

  gemm_mfma<<<2000, 512, 0, stream>>>(APk, Wrh, Wrl, Wih, Wil, ampsq);

  post_row<<<BS, 1024, 0, stream>>>(ampsq, bias, logits, logprobs, probs, tokens);
}

// Round 20
// 917.315 us; speedup vs baseline: 1.0803x; 1.0024x over previous
//
#include <hip/hip_runtime.h>

// Problem constants
#define BS   1024        // B*S rows
#define DD   1024        // D (= K)
#define VV   32000       // V
#define TOPK 50
#define TOPPF 0.95f
#define NVTOT 32768000ull   // BS*VV

typedef __attribute__((ext_vector_type(8))) short bf16x8;
typedef __attribute__((ext_vector_type(4))) float f32x4;
typedef __attribute__((ext_vector_type(4))) int   i32x4;

#define MFMA(A,B,C) __builtin_amdgcn_mfma_f32_16x16x32_bf16(A, B, C, 0, 0, 0)

// ---------------------------------------------------------------- utilities
__device__ __forceinline__ unsigned fkey(float f) {
  unsigned u = __float_as_uint(f);
  return (u & 0x80000000u) ? ~u : (u | 0x80000000u);
}
__device__ __forceinline__ unsigned rotl32(unsigned x, int r) {
  return (x << r) | (x >> (32 - r));
}
__device__ __forceinline__ ushort f2bf(float f) {   // fp32 -> bf16 RNE
  unsigned u = __float_as_uint(f);
  unsigned r = ((u >> 16) & 1u) + 0x7FFFu;
  return (ushort)((u + r) >> 16);
}
__device__ __forceinline__ float bf2f(ushort h) {
  return __uint_as_float(((unsigned)h) << 16);
}
__device__ __forceinline__ bf16x8 negbf(bf16x8 a) {  // flip sign of 8 bf16
  i32x4 t = __builtin_bit_cast(i32x4, a);
  t = t ^ 0x80008000;
  return __builtin_bit_cast(bf16x8, t);
}

// JAX threefry2x32-20, key=(0,42), partitionable: counter (0, i), bits = w0^w1.
__device__ float gumbel_at(unsigned i) {
  unsigned x0 = 0u, x1 = i;
  const unsigned ks0 = 0u, ks1 = 42u, ks2 = 0x1BD11BDAu ^ 0u ^ 42u;
  x0 += ks0; x1 += ks1;
  const int rotA[4] = {13, 15, 26, 6};
  const int rotB[4] = {17, 29, 16, 24};
#define TF_R4(R) { x0 += x1; x1 = rotl32(x1, R[0]); x1 ^= x0; \
                   x0 += x1; x1 = rotl32(x1, R[1]); x1 ^= x0; \
                   x0 += x1; x1 = rotl32(x1, R[2]); x1 ^= x0; \
                   x0 += x1; x1 = rotl32(x1, R[3]); x1 ^= x0; }
  TF_R4(rotA); x0 += ks1; x1 += ks2 + 1u;
  TF_R4(rotB); x0 += ks2; x1 += ks0 + 2u;
  TF_R4(rotA); x0 += ks0; x1 += ks1 + 3u;
  TF_R4(rotB); x0 += ks1; x1 += ks2 + 4u;
  TF_R4(rotA); x0 += ks2; x1 += ks0 + 5u;
#undef TF_R4
  unsigned bits = x0 ^ x1;
  float f = __uint_as_float(0x3F800000u | (bits >> 9)) - 1.0f;
  float u = fmaxf(f, 1.17549435e-38f);
  return -logf(-logf(u));
}

// ------------------------------------------------- split fp32 -> bf16 hi/lo
__device__ __forceinline__ void pack4(
    const float* __restrict__ xr, const float* __restrict__ xi,
    ushort* __restrict__ ohr, ushort* __restrict__ olr,
    ushort* __restrict__ ohi, ushort* __restrict__ oli,
    float si, int i) {
  float4 a = *(const float4*)(xr + i);
  float4 b = *(const float4*)(xi + i);
  float av[4] = {a.x, a.y, a.z, a.w};
  float bv[4] = {b.x * si, b.y * si, b.z * si, b.w * si};
  unsigned hr[4], lr[4], hi_[4], li[4];
#pragma unroll
  for (int j = 0; j < 4; ++j) {
    ushort h = f2bf(av[j]);          hr[j] = h;
    lr[j] = f2bf(av[j] - bf2f(h));
    ushort h2 = f2bf(bv[j]);         hi_[j] = h2;
    li[j] = f2bf(bv[j] - bf2f(h2));
  }
  uint2 w;
  w.x = hr[0] | (hr[1] << 16); w.y = hr[2] | (hr[3] << 16);
  *(uint2*)(ohr + i) = w;
  w.x = lr[0] | (lr[1] << 16); w.y = lr[2] | (lr[3] << 16);
  *(uint2*)(olr + i) = w;
  w.x = hi_[0] | (hi_[1] << 16); w.y = hi_[2] | (hi_[3] << 16);
  *(uint2*)(ohi + i) = w;
  w.x = li[0] | (li[1] << 16); w.y = li[2] | (li[3] << 16);
  *(uint2*)(oli + i) = w;
}

// single launch: blocks [0,1024) pack psi (imag negated); rest pack W.
__global__ __launch_bounds__(256) void pack_all(
    const float* __restrict__ pr, const float* __restrict__ pi,
    ushort* __restrict__ APk,
    const float* __restrict__ wr, const float* __restrict__ wi,
    ushort* __restrict__ Wrh, ushort* __restrict__ Wrl,
    ushort* __restrict__ Wih, ushort* __restrict__ Wil) {
  const int b = blockIdx.x;
  if (b < 1024) {
    int g = b * 256 + threadIdx.x;                 // n4 = 262144
    pack4(pr, pi, APk, APk + (1 << 20), APk + (2 << 20), APk + (3 << 20),
          -1.0f, g * 4);
  } else {
    int g = (b - 1024) * 256 + threadIdx.x;        // n4 = 8192000
    pack4(wr, wi, Wrh, Wrl, Wih, Wil, 1.0f, g * 4);
  }
}

// ---------------------------------------------------------------- MFMA GEMM
// R16 configuration verbatim (best measured: 645us, MfmaUtil 60%).
// amp_sq = |(Pr + iPi) . (Wr + iWi)|^2, split-bf16 (3-term), 12 MFMA/frag-pair.
// Block 128x128, 8 waves (2x4), wave tile 64x32, BK=32, double-buffered LDS,
// 2-barrier loop, XCD-partition remap.
__global__ __launch_bounds__(512) void gemm_mfma(
    const ushort* __restrict__ APk,                      // [4][1024][1024]
    const ushort* __restrict__ Wrh, const ushort* __restrict__ Wrl,
    const ushort* __restrict__ Wih, const ushort* __restrict__ Wil,
    float* __restrict__ amp) {
  __shared__ ushort lds[2][8][4096];   // 2 bufs x 8 tiles x (128r x 32k) = 128KB
  const int tid = threadIdx.x;
  const int lane = tid & 63, wid = tid >> 6;
  const int d = blockIdx.x;
  const int x = d & 7, s = d >> 3;
  const int bm = ((x >> 1) << 1) | (s & 1);       // bm-pair per XCD
  const int bn = (x & 1) * 125 + (s >> 1);        // bn-half per XCD
  const int row0 = bm << 7, col0 = bn << 7;
  const int wm = wid >> 2, wn = wid & 3;          // wave grid 2(M) x 4(N)

  const ushort* tp[8] = {APk, APk + (1 << 20), APk + (2 << 20), APk + (3 << 20),
                         Wrh, Wrl, Wih, Wil};

  // staging addressing (per thread, step-invariant part)
  const int rrow = tid >> 2;                     // tile row 0..127
  const int ss = (tid & 3) ^ (rrow & 3) ^ ((rrow >> 2) & 3);  // src slot
  const size_t offA = (size_t)(row0 + rrow) * DD + (ss << 3);
  const size_t offB = (size_t)(col0 + rrow) * DD + (ss << 3);

  f32x4 accr[4][2] = {}, acci[4][2] = {};

  // compute-side LDS byte offsets (step-invariant)
  int aoff[4], boff[2];
#pragma unroll
  for (int m = 0; m < 4; ++m) {
    const int ar = (wm << 6) + (m << 4) + (lane & 15);
    aoff[m] = (ar << 6) + ((((lane >> 4)) ^ (ar & 3) ^ ((ar >> 2) & 3)) << 4);
  }
#pragma unroll
  for (int n = 0; n < 2; ++n) {
    const int br = (wn << 5) + (n << 4) + (lane & 15);
    boff[n] = (br << 6) + ((((lane >> 4)) ^ (br & 3) ^ ((br >> 2) & 3)) << 4);
  }

#define STAGE(buf, step) {                                                   \
    const int k0 = (step) << 5;                                              \
    _Pragma("unroll")                                                        \
    for (int t = 0; t < 8; ++t) {                                            \
      const ushort* src = tp[t] + ((t < 4) ? offA : offB) + k0;              \
      __builtin_amdgcn_global_load_lds(                                      \
          (const __attribute__((address_space(1))) unsigned int*)src,        \
          (__attribute__((address_space(3))) unsigned int*)&lds[buf][t][wid << 9], \
          16, 0, 0);                                                         \
    }                                                                        \
  }

  STAGE(0, 0);
  __syncthreads();
  int cur = 0;
  for (int step = 0; step < 32; ++step) {
    if (step + 1 < 32) STAGE(cur ^ 1, step + 1);
    const char* L0 = (const char*)&lds[cur][0][0];
    const char* L1 = (const char*)&lds[cur][1][0];
    const char* L2 = (const char*)&lds[cur][2][0];
    const char* L3 = (const char*)&lds[cur][3][0];
    const char* L4 = (const char*)&lds[cur][4][0];
    const char* L5 = (const char*)&lds[cur][5][0];
    const char* L6 = (const char*)&lds[cur][6][0];
    const char* L7 = (const char*)&lds[cur][7][0];
    bf16x8 aPrh[4], aPrl[4], aNih[4], aNil[4], aPih[4], aPil[4];
#pragma unroll
    for (int m = 0; m < 4; ++m) {
      aPrh[m] = *(const bf16x8*)(L0 + aoff[m]);
      aPrl[m] = *(const bf16x8*)(L1 + aoff[m]);
      aNih[m] = *(const bf16x8*)(L2 + aoff[m]);
      aNil[m] = *(const bf16x8*)(L3 + aoff[m]);
      aPih[m] = negbf(aNih[m]);
      aPil[m] = negbf(aNil[m]);
    }
#pragma unroll
    for (int n = 0; n < 2; ++n) {
      bf16x8 bRh = *(const bf16x8*)(L4 + boff[n]);
      bf16x8 bRl = *(const bf16x8*)(L5 + boff[n]);
      bf16x8 bIh = *(const bf16x8*)(L6 + boff[n]);
      bf16x8 bIl = *(const bf16x8*)(L7 + boff[n]);
#pragma unroll
      for (int m = 0; m < 4; ++m) {
        f32x4 r = accr[m][n], q = acci[m][n];
        r = MFMA(aPrh[m], bRh, r); r = MFMA(aPrh[m], bRl, r); r = MFMA(aPrl[m], bRh, r);
        r = MFMA(aNih[m], bIh, r); r = MFMA(aNih[m], bIl, r); r = MFMA(aNil[m], bIh, r);
        q = MFMA(aPih[m], bRh, q); q = MFMA(aPih[m], bRl, q); q = MFMA(aPil[m], bRh, q);
        q = MFMA(aPrh[m], bIh, q); q = MFMA(aPrh[m], bIl, q); q = MFMA(aPrl[m], bIh, q);
        accr[m][n] = r; acci[m][n] = q;
      }
    }
    __syncthreads();   // drains vmcnt(0): next buffer staged; all reads done
    cur ^= 1;
  }
#undef STAGE
  // epilogue: C/D mapping col=lane&15, row=(lane>>4)*4+reg
#pragma unroll
  for (int m = 0; m < 4; ++m)
#pragma unroll
    for (int n = 0; n < 2; ++n)
#pragma unroll
      for (int qi = 0; qi < 4; ++qi) {
        const int row = row0 + (wm << 6) + (m << 4) + ((lane >> 4) << 2) + qi;
        const int col = col0 + (wn << 5) + (n << 4) + (lane & 15);
        float vr = accr[m][n][qi], vi = acci[m][n][qi];
        amp[(size_t)row * VV + col] = vr * vr + vi * vi;
      }
}

// ---------------------------------------------------------- fused row post
// 1024 threads; shfl-based reductions; single-wave shfl scan for the top-k
// histogram (2 barriers instead of 18); logprobs merged into probs pass;
// NT stores for streaming outputs.
__global__ __launch_bounds__(1024) void post_row(
    const float* __restrict__ amp, const float* __restrict__ bias,
    float* __restrict__ logits, float* __restrict__ logprobs,
    float* __restrict__ probs, float* __restrict__ tokens) {
  __shared__ __align__(16) float lg[VV];      // 128000 B
  __shared__ int hist[4096];                  // 16384 B (also reduce scratch)
  __shared__ int iscan[512];                  // 2048 B
  __shared__ float sval[768]; __shared__ int sidx[768];
  __shared__ float ssv[768];  __shared__ int ssi[768];
  __shared__ int scnt;
  __shared__ float sh_f[4];   // 0:red-out 1:mx2 2:dk 3:vb
  __shared__ int   sh_i[4];   // 0:chunk 1:bin 2:ib

  const int row = blockIdx.x, tid = threadIdx.x;
  const int lane = tid & 63, wv = tid >> 6;   // 16 waves
  const float* A = amp + (size_t)row * VV;
  float* Lg = logits + (size_t)row * VV;
  float* Lp = logprobs + (size_t)row * VV;
  float* P  = probs + (size_t)row * VV;
  float* redf = (float*)hist;                 // 16 wave partials

  // pass 1: load amp -> LDS, row sum (wave shfl + serial-16 tail)
  float s = 0.f;
  for (int i = tid; i < VV / 4; i += 1024) {
    float4 a = ((const float4*)A)[i];
    ((float4*)lg)[i] = a;
    s += a.x + a.y + a.z + a.w;
  }
#pragma unroll
  for (int o = 32; o > 0; o >>= 1) s += __shfl_down(s, o, 64);
  if (lane == 0) redf[wv] = s;
  __syncthreads();
  if (tid == 0) {
    float t = 0.f;
    for (int j = 0; j < 16; ++j) t += redf[j];
    sh_f[0] = t * (1.0f / (float)VV) * 1e-6f + 1e-30f;
  }
  __syncthreads();
  const float floorv = sh_f[0];
  __syncthreads();

  // pass 2: logits = log(amp+floor)+bias; store LDS + global (NT); track max
  float mx = -INFINITY;
  for (int i = tid; i < VV / 4; i += 1024) {
    float4 a = ((float4*)lg)[i];
    float4 b = ((const float4*)bias)[i];
    f32x4 l;
    l.x = logf(a.x + floorv) + b.x;
    l.y = logf(a.y + floorv) + b.y;
    l.z = logf(a.z + floorv) + b.z;
    l.w = logf(a.w + floorv) + b.w;
    ((f32x4*)lg)[i] = l;
    __builtin_nontemporal_store(l, (f32x4*)Lg + i);
    mx = fmaxf(mx, fmaxf(fmaxf(l.x, l.y), fmaxf(l.z, l.w)));
  }
#pragma unroll
  for (int o = 32; o > 0; o >>= 1) mx = fmaxf(mx, __shfl_down(mx, o, 64));
  if (lane == 0) redf[wv] = mx;
  __syncthreads();
  if (tid == 0) {
    float t = -INFINITY;
    for (int j = 0; j < 16; ++j) t = fmaxf(t, redf[j]);
    sh_f[0] = t;
  }
  __syncthreads();
  mx = sh_f[0];
  __syncthreads();

  // pass 3: sumexp
  float se = 0.f;
  for (int i = tid; i < VV / 4; i += 1024) {
    float4 l = ((float4*)lg)[i];
    se += expf(l.x - mx) + expf(l.y - mx) + expf(l.z - mx) + expf(l.w - mx);
  }
#pragma unroll
  for (int o = 32; o > 0; o >>= 1) se += __shfl_down(se, o, 64);
  if (lane == 0) redf[wv] = se;
  __syncthreads();
  if (tid == 0) {
    float t = 0.f;
    for (int j = 0; j < 16; ++j) t += redf[j];
    sh_f[0] = mx + logf(t);
  }
  __syncthreads();
  const float lse = sh_f[0];
  __syncthreads();   // redf (hist) free after this point

  // pass 4: 12-bit histogram of fkey(logits)
  for (int i = tid; i < 4096; i += 1024) hist[i] = 0;
  if (tid == 0) scnt = 0;
  __syncthreads();
  for (int v = tid; v < VV; v += 1024)
    atomicAdd(&hist[fkey(lg[v]) >> 20], 1);
  __syncthreads();
  // per-chunk counts (8 bins descending per chunk), then single-wave shfl
  // inclusive scan over the 512 chunks (wave 0; 8 segments with carry).
  {
    if (tid < 512) {
      const int hi = 4095 - 8 * tid;
      int part = 0;
#pragma unroll
      for (int j = 0; j < 8; ++j) part += hist[hi - j];
      iscan[tid] = part;
    }
    __syncthreads();
    if (wv == 0) {
      int carry = 0;
#pragma unroll
      for (int seg = 0; seg < 8; ++seg) {
        int v = iscan[seg * 64 + lane];
#pragma unroll
        for (int o = 1; o < 64; o <<= 1) {
          int t = __shfl_up(v, o, 64);
          if (lane >= o) v += t;
        }
        v += carry;
        iscan[seg * 64 + lane] = v;
        carry = __shfl(v, 63, 64);
      }
    }
    __syncthreads();
    if (tid < 512) {
      int cum = iscan[tid], prev = tid ? iscan[tid - 1] : 0;
      if (cum >= TOPK && prev < TOPK) sh_i[0] = tid;
    }
    __syncthreads();
    if (tid == 0) {
      int tc = sh_i[0];
      int c = tc ? iscan[tc - 1] : 0;
      int b = 4095 - 8 * tc;
      for (int j = 0; j < 8; ++j) {
        int h = hist[4095 - 8 * tc - j];
        if (c + h >= TOPK) { b = 4095 - 8 * tc - j; break; }
        c += h;
      }
      sh_i[1] = b;
    }
    __syncthreads();
  }
  const unsigned binb = (unsigned)sh_i[1];

  // gather survivors (all elems in bins >= binb; superset of top-k)
  for (int v = tid; v < VV; v += 1024) {
    if ((fkey(lg[v]) >> 20) >= binb) {
      int p = atomicAdd(&scnt, 1);
      if (p < 768) { sval[p] = lg[v]; sidx[p] = v; }
    }
  }
  __syncthreads();
  const int n = min(scnt, 768);
  // rank sort: value desc, index asc (stable argsort(-filt) order)
  for (int i = tid; i < n; i += 1024) {
    float vi = sval[i]; int ii = sidx[i]; int r = 0;
    for (int j = 0; j < n; ++j) {
      float vj = sval[j]; int ij = sidx[j];
      r += (vj > vi) || (vj == vi && ij < ii);
    }
    ssv[r] = vi; ssi[r] = ii;
  }
  __syncthreads();
  if (tid == 0) {
    const float kthv = ssv[TOPK - 1];
    int np = TOPK;
    while (np < n && ssv[np] >= kthv) ++np;
    const float mx2 = ssv[0];
    float denom = 0.f;
    for (int j = 0; j < np; ++j) denom += expf(ssv[j] - mx2);
    float cum = 0.f; int m = np;
    for (int j = 0; j < np; ++j) {
      float sp = expf(ssv[j] - mx2) / denom;
      cum += sp;
      if (cum - sp >= TOPPF) { m = j; break; }
    }
    float dk = 0.f;
    for (int j = 0; j < m; ++j) dk += expf(ssv[j] - mx2);
    sh_f[1] = mx2; sh_f[2] = dk; sh_f[3] = ssv[m - 1];
    sh_i[2] = ssi[m - 1];
  }
  __syncthreads();
  const float mx2 = sh_f[1], dk = sh_f[2], vb = sh_f[3];
  const int ib = sh_i[2];

  // pass 5: logprobs + probs + gumbel argmax (merged single sweep, NT stores)
  float best = -INFINITY; int bidx = 0x7FFFFFFF;
  for (int i = tid; i < VV / 4; i += 1024) {
    float4 l4 = ((float4*)lg)[i];
    float lv[4] = {l4.x, l4.y, l4.z, l4.w};
    f32x4 o4 = {l4.x - lse, l4.y - lse, l4.z - lse, l4.w - lse};
    __builtin_nontemporal_store(o4, (f32x4*)Lp + i);
    float pv[4] = {0.f, 0.f, 0.f, 0.f};
#pragma unroll
    for (int j = 0; j < 4; ++j) {
      const int v = i * 4 + j;
      float l = lv[j];
      bool kept = (l > vb) || (l == vb && v <= ib);
      if (kept) {
        pv[j] = expf(l - mx2) / dk;
        float g = gumbel_at((unsigned)(row * VV + v));
        float sc = l + g;
        if (sc > best || (sc == best && v < bidx)) { best = sc; bidx = v; }
      }
    }
    f32x4 p4 = {pv[0], pv[1], pv[2], pv[3]};
    __builtin_nontemporal_store(p4, (f32x4*)P + i);
  }
  // argmax reduce: wave shfl, then serial-16 (scratch = hist space)
#pragma unroll
  for (int o = 32; o > 0; o >>= 1) {
    float ov = __shfl_down(best, o, 64);
    int   oi = __shfl_down(bidx, o, 64);
    if (ov > best || (ov == best && oi < bidx)) { best = ov; bidx = oi; }
  }
  {
    float* wv_v = (float*)hist;          // 16 floats
    int*   wv_i = hist + 16;             // 16 ints
    if (lane == 0) { wv_v[wv] = best; wv_i[wv] = bidx; }
    __syncthreads();
    if (tid == 0) {
      float bv = -INFINITY; int bi = 0x7FFFFFFF;
      for (int j = 0; j < 16; ++j) {
        if (wv_v[j] > bv || (wv_v[j] == bv && wv_i[j] < bi)) { bv = wv_v[j]; bi = wv_i[j]; }
      }
      tokens[row] = (float)bi;
    }
  }
}

// ---------------------------------------------------------------- launcher
extern "C" void kernel_launch(void* const* d_in, const int* in_sizes, int n_in,
                              void* d_out, int out_size, void* d_ws, size_t ws_size,
                              hipStream_t stream) {
  const float* pr   = (const float*)d_in[0];
  const float* pi   = (const float*)d_in[1];
  const float* wr   = (const float*)d_in[2];
  const float* wi   = (const float*)d_in[3];
  const float* bias = (const float*)d_in[4];

  float* out      = (float*)d_out;
  float* logits   = out;                       // [1024, 32000]
  float* logprobs = out + NVTOT;               // [1024, 32000]
  float* ampsq    = out + 2 * NVTOT;           // [1024, 32000]
  float* tokens   = out + 3 * NVTOT;           // [1024]
  float* probs    = out + 3 * NVTOT + 1024;    // [1024, 32000]

  // scratch-in-output: W bf16 packs live in logits+logprobs (overwritten by
  // post_row AFTER the GEMM); psi packs live in probs (overwritten last).
  ushort* Wrh = (ushort*)logits;               // [32000][1024] each
  ushort* Wrl = Wrh + 32768000;
  ushort* Wih = (ushort*)logprobs;
  ushort* Wil = Wih + 32768000;
  ushort* APk = (ushort*)probs;                // [4][1024][1024]

  // pack psi (negated imag) and W into bf16 hi/lo -- single launch
  pack_all<<<33024, 256, 0, stream>>>(pr, pi, APk, wr, wi, Wrh, Wrl, Wih, Wil);

  gemm_mfma<<<2000, 512, 0, stream>>>(APk, Wrh, Wrl, Wih, Wil, ampsq);

  post_row<<<BS, 1024, 0, stream>>>(ampsq, bias, logits, logprobs, probs, tokens);
}